// Round 1
// baseline (711.528 us; speedup 1.0000x reference)
//
#include <hip/hip_runtime.h>

#define B_ 4
#define T_ 2048
#define D_ 128
#define H_ 8
#define DK_ 16

typedef __attribute__((ext_vector_type(8))) short short8;
typedef __attribute__((ext_vector_type(4))) float floatx4;

__device__ __forceinline__ short f2bf(float x) {
    unsigned u = __builtin_bit_cast(unsigned, x);
    u += 0x7FFFu + ((u >> 16) & 1u);   // RNE
    return (short)(u >> 16);
}

// ---------------------------------------------------------------------------
// Kernel 1: QKV projections.  grid = 3*512 blocks, 64 threads.
// Q stored bf16 [bh][t][16] pre-scaled by 0.25; K bf16 [bh][t][16];
// V stored transposed bf16 [bh][16][t].
// ---------------------------------------------------------------------------
__global__ __launch_bounds__(64) void qkv_kernel(
    const float* __restrict__ q_in, const float* __restrict__ k_in,
    const float* __restrict__ v_in,
    const float* __restrict__ Wq, const float* __restrict__ bq,
    const float* __restrict__ Wk, const float* __restrict__ bk,
    const float* __restrict__ Wv, const float* __restrict__ bv,
    short* __restrict__ q_ws, short* __restrict__ k_ws, short* __restrict__ vt_ws)
{
    int mat = blockIdx.x >> 9;          // 0=Q 1=K 2=V
    int rb  = blockIdx.x & 511;
    int row0 = rb * 16;                 // global row in [0, 8192)
    int b  = row0 >> 11;
    int t0 = row0 & (T_ - 1);

    const float* X    = (mat == 0) ? q_in : (mat == 1) ? k_in : v_in;
    const float* W    = (mat == 0) ? Wq   : (mat == 1) ? Wk   : Wv;
    const float* bias = (mat == 0) ? bq   : (mat == 1) ? bk   : bv;

    __shared__ float xt[16][128];
    int tid = threadIdx.x;
    #pragma unroll
    for (int i = 0; i < 8; ++i) {
        int idx = tid + i * 64;         // 512 float4 chunks
        int r = idx >> 5, c4 = idx & 31;
        *(float4*)&xt[r][c4 * 4] =
            *(const float4*)&X[(size_t)(row0 + r) * 128 + c4 * 4];
    }
    __syncthreads();

    int c0 = tid, c1 = tid + 64;
    float accA[16], accB[16];
    float b0 = bias[c0], b1 = bias[c1];
    #pragma unroll
    for (int r = 0; r < 16; ++r) { accA[r] = b0; accB[r] = b1; }

    for (int d4 = 0; d4 < 32; ++d4) {
        float w0[4], w1[4];
        #pragma unroll
        for (int j = 0; j < 4; ++j) {
            w0[j] = W[(d4 * 4 + j) * 128 + c0];
            w1[j] = W[(d4 * 4 + j) * 128 + c1];
        }
        #pragma unroll
        for (int r = 0; r < 16; ++r) {
            float4 xv = *(const float4*)&xt[r][d4 * 4];
            accA[r] += xv.x * w0[0] + xv.y * w0[1] + xv.z * w0[2] + xv.w * w0[3];
            accB[r] += xv.x * w1[0] + xv.y * w1[1] + xv.z * w1[2] + xv.w * w1[3];
        }
    }

    int hA = c0 >> 4, dA = c0 & 15;
    int hB = c1 >> 4, dB = c1 & 15;
    #pragma unroll
    for (int r = 0; r < 16; ++r) {
        int t = t0 + r;
        float vA = accA[r], vB = accB[r];
        if (mat == 0) { vA *= 0.25f; vB *= 0.25f; }   // fold 1/sqrt(dk) into Q
        if (mat == 2) {
            vt_ws[((size_t)(b * H_ + hA) * DK_ + dA) * T_ + t] = f2bf(vA);
            vt_ws[((size_t)(b * H_ + hB) * DK_ + dB) * T_ + t] = f2bf(vB);
        } else {
            short* dst = (mat == 0) ? q_ws : k_ws;
            dst[((size_t)(b * H_ + hA) * T_ + t) * DK_ + dA] = f2bf(vA);
            dst[((size_t)(b * H_ + hB) * T_ + t) * DK_ + dB] = f2bf(vB);
        }
    }
}

// ---------------------------------------------------------------------------
// Kernel 2: attention.  grid = 32 bh * 8 qchunks = 256 blocks, 512 threads.
// K and V^T staged in LDS (bf16); two-pass softmax (no max-pass: scores are
// O(+-10), exp() is fp32-safe); MFMA 16x16x32 with dk zero-padded to 32 for
// QK^T, full K=32 for PV.  attn written normalized fp32 (nontemporal).
// ---------------------------------------------------------------------------
__global__ __launch_bounds__(512) void attn_kernel(
    const short* __restrict__ q_ws, const short* __restrict__ k_ws,
    const short* __restrict__ vt_ws,
    float* __restrict__ attn, float* __restrict__ ctx_ws)
{
    __shared__ short klds[T_ * DK_];          // 65536 B, row pitch 32 B
    __shared__ short vtlds[DK_ * (T_ + 8)];   // 65792 B, row pitch 4112 B (16-aligned)
    __shared__ short tblds[8 * 16 * 40];      // 10240 B, per-wave 16x32 tile, pitch 80 B

    int tid = threadIdx.x;
    int bh = blockIdx.x >> 3;
    int qc = blockIdx.x & 7;
    int b = bh >> 3, h = bh & 7;

    const short* kbase  = k_ws  + (size_t)bh * T_ * DK_;
    const short* vtbase = vt_ws + (size_t)bh * DK_ * T_;

    #pragma unroll
    for (int i = 0; i < 8; ++i) {             // stage K: 4096 16B chunks
        int idx = tid + i * 512;
        *(short8*)&klds[idx * 8] = *(const short8*)&kbase[idx * 8];
    }
    #pragma unroll
    for (int i = 0; i < 8; ++i) {             // stage V^T with +8 row pad
        int idx = tid + i * 512;
        int d = idx >> 8, off = idx & 255;
        *(short8*)&vtlds[d * (T_ + 8) + off * 8] =
            *(const short8*)&vtbase[d * T_ + off * 8];
    }
    __syncthreads();

    int wid = tid >> 6, lane = tid & 63;
    int l15 = lane & 15, quad = lane >> 4;
    short8 z8 = {0, 0, 0, 0, 0, 0, 0, 0};

    float* attn_bh = attn + (size_t)bh * T_ * T_;

    for (int tt = 0; tt < 2; ++tt) {
        int qrow0 = qc * 256 + tt * 128 + wid * 16;

        // Q A-frag: A[m=lane&15][k=quad*8+j]; quads 2,3 are the dk pad -> zero
        short8 aq = *(const short8*)
            &q_ws[((size_t)bh * T_ + qrow0 + l15) * DK_ + (quad & 1) * 8];
        if (quad >= 2) aq = z8;

        // ---- pass 1: row sums of exp(s) ----
        float l[4] = {0.f, 0.f, 0.f, 0.f};
        for (int tk0 = 0; tk0 < T_; tk0 += 32) {
            short8 bk0 = *(const short8*)&klds[(tk0 + l15) * DK_ + (quad & 1) * 8];
            short8 bk1 = *(const short8*)&klds[(tk0 + 16 + l15) * DK_ + (quad & 1) * 8];
            if (quad >= 2) { bk0 = z8; bk1 = z8; }
            floatx4 s0 = __builtin_amdgcn_mfma_f32_16x16x32_bf16(
                aq, bk0, (floatx4){0.f, 0.f, 0.f, 0.f}, 0, 0, 0);
            floatx4 s1 = __builtin_amdgcn_mfma_f32_16x16x32_bf16(
                aq, bk1, (floatx4){0.f, 0.f, 0.f, 0.f}, 0, 0, 0);
            #pragma unroll
            for (int r = 0; r < 4; ++r)
                l[r] += __expf(s0[r]) + __expf(s1[r]);
        }
        #pragma unroll
        for (int r = 0; r < 4; ++r) {         // reduce over the 16 cols
            #pragma unroll
            for (int off = 1; off < 16; off <<= 1)
                l[r] += __shfl_xor(l[r], off);
            l[r] = 1.0f / l[r];               // now inv_l, broadcast in quad
        }

        // ---- pass 2: recompute S, write attn, accumulate ctx = P V ----
        short* tb = &tblds[wid * 16 * 40];
        floatx4 ctx = {0.f, 0.f, 0.f, 0.f};
        float* rowp[4];
        #pragma unroll
        for (int r = 0; r < 4; ++r)
            rowp[r] = attn_bh + (size_t)(qrow0 + quad * 4 + r) * T_ + l15;

        for (int tk0 = 0; tk0 < T_; tk0 += 32) {
            short8 bk0 = *(const short8*)&klds[(tk0 + l15) * DK_ + (quad & 1) * 8];
            short8 bk1 = *(const short8*)&klds[(tk0 + 16 + l15) * DK_ + (quad & 1) * 8];
            if (quad >= 2) { bk0 = z8; bk1 = z8; }
            floatx4 s0 = __builtin_amdgcn_mfma_f32_16x16x32_bf16(
                aq, bk0, (floatx4){0.f, 0.f, 0.f, 0.f}, 0, 0, 0);
            floatx4 s1 = __builtin_amdgcn_mfma_f32_16x16x32_bf16(
                aq, bk1, (floatx4){0.f, 0.f, 0.f, 0.f}, 0, 0, 0);
            #pragma unroll
            for (int r = 0; r < 4; ++r) {
                float p0 = __expf(s0[r]) * l[r];
                float p1 = __expf(s1[r]) * l[r];
                __builtin_nontemporal_store(p0, rowp[r] + tk0);
                __builtin_nontemporal_store(p1, rowp[r] + tk0 + 16);
                tb[(quad * 4 + r) * 40 + l15]      = f2bf(p0);   // C->A transpose
                tb[(quad * 4 + r) * 40 + 16 + l15] = f2bf(p1);
            }
            short8 pa = *(const short8*)&tb[l15 * 40 + quad * 8];            // P A-frag
            short8 vb = *(const short8*)&vtlds[l15 * (T_ + 8) + tk0 + quad * 8]; // V B-frag
            ctx = __builtin_amdgcn_mfma_f32_16x16x32_bf16(pa, vb, ctx, 0, 0, 0);
        }
        #pragma unroll
        for (int r = 0; r < 4; ++r)
            ctx_ws[((size_t)b * T_ + qrow0 + quad * 4 + r) * D_ + h * DK_ + l15] =
                ctx[r];
    }
}

// ---------------------------------------------------------------------------
// Kernel 3: out-proj + residual + LayerNorm.  grid = 512 blocks, 256 threads;
// one wave handles 4 rows, lane owns cols (lane, lane+64).
// ---------------------------------------------------------------------------
__global__ __launch_bounds__(256) void outln_kernel(
    const float* __restrict__ ctx_ws, const float* __restrict__ Wo,
    const float* __restrict__ bo, const float* __restrict__ q_in,
    const float* __restrict__ gamma, const float* __restrict__ beta,
    float* __restrict__ out)
{
    __shared__ float xrow[4][4][128];
    int tid = threadIdx.x, wid = tid >> 6, lane = tid & 63;
    int row0 = blockIdx.x * 16 + wid * 4;

    #pragma unroll
    for (int r = 0; r < 4; ++r) {
        xrow[wid][r][lane]      = ctx_ws[(size_t)(row0 + r) * 128 + lane];
        xrow[wid][r][lane + 64] = ctx_ws[(size_t)(row0 + r) * 128 + lane + 64];
    }

    float acc0[4], acc1[4];
    float bb0 = bo[lane], bb1 = bo[lane + 64];
    #pragma unroll
    for (int r = 0; r < 4; ++r) { acc0[r] = bb0; acc1[r] = bb1; }

    for (int d4 = 0; d4 < 32; ++d4) {
        float w0[4], w1[4];
        #pragma unroll
        for (int j = 0; j < 4; ++j) {
            w0[j] = Wo[(d4 * 4 + j) * 128 + lane];
            w1[j] = Wo[(d4 * 4 + j) * 128 + lane + 64];
        }
        #pragma unroll
        for (int r = 0; r < 4; ++r) {
            float4 xv = *(const float4*)&xrow[wid][r][d4 * 4];
            acc0[r] += xv.x * w0[0] + xv.y * w0[1] + xv.z * w0[2] + xv.w * w0[3];
            acc1[r] += xv.x * w1[0] + xv.y * w1[1] + xv.z * w1[2] + xv.w * w1[3];
        }
    }

    float g0 = gamma[lane], g1 = gamma[lane + 64];
    float be0 = beta[lane], be1 = beta[lane + 64];
    #pragma unroll
    for (int r = 0; r < 4; ++r) {
        size_t row = row0 + r;
        float x0 = acc0[r] + q_in[row * 128 + lane];
        float x1 = acc1[r] + q_in[row * 128 + lane + 64];
        float s = x0 + x1, s2 = x0 * x0 + x1 * x1;
        #pragma unroll
        for (int off = 1; off < 64; off <<= 1) {
            s  += __shfl_xor(s, off);
            s2 += __shfl_xor(s2, off);
        }
        float mean = s * (1.0f / 128.0f);
        float var  = s2 * (1.0f / 128.0f) - mean * mean;
        float rstd = rsqrtf(var + 1e-5f);
        out[row * 128 + lane]      = (x0 - mean) * rstd * g0 + be0;
        out[row * 128 + lane + 64] = (x1 - mean) * rstd * g1 + be1;
    }
}

// ---------------------------------------------------------------------------
extern "C" void kernel_launch(void* const* d_in, const int* in_sizes, int n_in,
                              void* d_out, int out_size, void* d_ws, size_t ws_size,
                              hipStream_t stream)
{
    const float* queries = (const float*)d_in[0];
    const float* keys    = (const float*)d_in[1];
    const float* values  = (const float*)d_in[2];
    const float* Wq = (const float*)d_in[3];  const float* bq = (const float*)d_in[4];
    const float* Wk = (const float*)d_in[5];  const float* bk = (const float*)d_in[6];
    const float* Wv = (const float*)d_in[7];  const float* bv = (const float*)d_in[8];
    const float* Wo = (const float*)d_in[9];  const float* bo = (const float*)d_in[10];
    const float* gamma = (const float*)d_in[11];
    const float* beta  = (const float*)d_in[12];

    // workspace layout: Q bf16 2MB | K bf16 2MB | V^T bf16 2MB | ctx f32 4MB
    short* q_ws  = (short*)d_ws;
    short* k_ws  = q_ws  + (1 << 20);
    short* vt_ws = k_ws  + (1 << 20);
    float* ctx_ws = (float*)(vt_ws + (1 << 20));

    float* out  = (float*)d_out;
    float* attn = out + (size_t)B_ * T_ * D_;

    qkv_kernel<<<dim3(3 * 512), dim3(64), 0, stream>>>(
        queries, keys, values, Wq, bq, Wk, bk, Wv, bv, q_ws, k_ws, vt_ws);
    attn_kernel<<<dim3(256), dim3(512), 0, stream>>>(
        q_ws, k_ws, vt_ws, attn, ctx_ws);
    outln_kernel<<<dim3(512), dim3(256), 0, stream>>>(
        ctx_ws, Wo, bo, queries, gamma, beta, out);
}